// Round 5
// baseline (515.137 us; speedup 1.0000x reference)
//
#include <hip/hip_runtime.h>

#define DEV __device__ __forceinline__

typedef __attribute__((ext_vector_type(8))) short short8;
typedef __attribute__((ext_vector_type(4))) float f32x4;
typedef __attribute__((ext_vector_type(4))) unsigned short ushort4_t;
typedef __attribute__((ext_vector_type(4))) unsigned int uint4_t;

namespace {
constexpr int D_ = 256, C_ = 10, T_ = 15, H_ = 5, ENC_ = 64, L_ = 16;
constexpr int NS_ = 2048, NQ_ = 32768;
constexpr int P_ = 60240, SW_ = 57600, SB_ = 225, LF_ = 2400;
constexpr int FEAT_ = 128;
constexpr int G_ = 75;                      // H*T groups
constexpr int GC_ = 25;                     // groups per chunk (3 chunks)
constexpr int WGB_ = 16384;                 // bytes per group W-image

// workspace layout (in floats)
constexpr size_t OFF_H1   = 0;
constexpr size_t OFF_H2   = OFF_H1 + (size_t)H_*NS_*ENC_;
constexpr size_t OFF_CTX  = OFF_H2 + (size_t)H_*NS_*ENC_;
constexpr size_t OFF_PVEC = OFF_CTX + (size_t)H_*ENC_;
constexpr size_t OFF_TMP  = OFF_PVEC + (size_t)H_*FEAT_;
constexpr size_t OFF_SB   = OFF_TMP + 8;
constexpr size_t OFF_LRAW = OFF_SB + (size_t)H_*T_*T_;
constexpr size_t OFF_TRAW = OFF_LRAW + (size_t)H_*T_*L_*C_;
constexpr size_t OFF_SL   = OFF_TRAW + (size_t)H_*T_;
constexpr size_t OFF_WBF  = OFF_SL + (size_t)H_*T_*L_*C_;       // 75*16384B
constexpr size_t OFF_SLA  = OFF_WBF + (size_t)G_*WGB_/4;        // 75*1024B
constexpr size_t OFF_OUTP = OFF_SLA + (size_t)G_*1024/4;        // 3*NQ*10 floats
constexpr size_t WS_NEED_FLOATS = OFF_OUTP + (size_t)3*NQ_*10;
} // namespace

DEV float wave_sum(float v) {
  #pragma unroll
  for (int o = 32; o; o >>= 1) v += __shfl_xor(v, o, 64);
  return v;
}
DEV float gelu_exact(float x) { return 0.5f * x * (1.f + erff(x * 0.70710678118654752f)); }
DEV unsigned short f2bf(float x) {            // RNE bf16
  unsigned u = __float_as_uint(x);
  return (unsigned short)((u + 0x7FFFu + ((u >> 16) & 1u)) >> 16);
}
DEV float bf2f(unsigned short b) { return __uint_as_float(((unsigned)b) << 16); }
DEV unsigned cvt_pk_bf16(float lo, float hi) {
  unsigned d;
  asm("v_cvt_pk_bf16_f32 %0, %1, %2" : "=v"(d) : "v"(lo), "v"(hi));
  return d;
}

// ---------------- encoder: h = gelu(LN(X @ W + b)), one wave per 4 rows ----------------
__global__ __launch_bounds__(256) void enc1_kernel(
    const float* __restrict__ Xbase,
    const float* __restrict__ W, const float* __restrict__ bias,
    const float* __restrict__ gam, const float* __restrict__ bet,
    float* __restrict__ Out)
{
  constexpr int K = 256;
  const int h = blockIdx.y;
  const int lane = threadIdx.x & 63;
  const int wv = threadIdx.x >> 6;
  const int row0 = blockIdx.x * 16 + wv * 4;
  const float* __restrict__ X = Xbase + (size_t)row0 * K;
  const float* __restrict__ wc = W + (size_t)h * K * ENC_ + lane;
  float a0 = 0.f, a1 = 0.f, a2 = 0.f, a3 = 0.f;
  #pragma unroll 4
  for (int k = 0; k < K; ++k) {
    const float wkl = wc[(size_t)k * ENC_];
    a0 = fmaf(X[k],       wkl, a0);
    a1 = fmaf(X[K + k],   wkl, a1);
    a2 = fmaf(X[2*K + k], wkl, a2);
    a3 = fmaf(X[3*K + k], wkl, a3);
  }
  const float bb = bias[h*ENC_ + lane];
  const float gg = gam[h*ENC_ + lane], be2 = bet[h*ENC_ + lane];
  float acc[4] = {a0 + bb, a1 + bb, a2 + bb, a3 + bb};
  #pragma unroll
  for (int r = 0; r < 4; ++r) {
    const float m = wave_sum(acc[r]) * (1.f / ENC_);
    const float d = acc[r] - m;
    const float var = wave_sum(d * d) * (1.f / ENC_);
    const float y = d * rsqrtf(var + 1e-5f) * gg + be2;
    Out[((size_t)h * NS_ + row0 + r) * ENC_ + lane] = gelu_exact(y);
  }
}

__global__ __launch_bounds__(256) void enc2_kernel(
    const float* __restrict__ Xbase,
    const float* __restrict__ W, const float* __restrict__ bias,
    const float* __restrict__ gam, const float* __restrict__ bet,
    float* __restrict__ Out)
{
  constexpr int K = 64;
  const int h = blockIdx.y;
  const int lane = threadIdx.x & 63;
  const int wv = threadIdx.x >> 6;
  const int row0 = blockIdx.x * 16 + wv * 4;
  const float* __restrict__ X = Xbase + (size_t)h * NS_ * ENC_ + (size_t)row0 * K;
  const float* __restrict__ wc = W + (size_t)h * K * ENC_ + lane;
  float a0 = 0.f, a1 = 0.f, a2 = 0.f, a3 = 0.f;
  #pragma unroll 4
  for (int k = 0; k < K; ++k) {
    const float wkl = wc[(size_t)k * ENC_];
    a0 = fmaf(X[k],       wkl, a0);
    a1 = fmaf(X[K + k],   wkl, a1);
    a2 = fmaf(X[2*K + k], wkl, a2);
    a3 = fmaf(X[3*K + k], wkl, a3);
  }
  const float bb = bias[h*ENC_ + lane];
  const float gg = gam[h*ENC_ + lane], be2 = bet[h*ENC_ + lane];
  float acc[4] = {a0 + bb, a1 + bb, a2 + bb, a3 + bb};
  #pragma unroll
  for (int r = 0; r < 4; ++r) {
    const float m = wave_sum(acc[r]) * (1.f / ENC_);
    const float d = acc[r] - m;
    const float var = wave_sum(d * d) * (1.f / ENC_);
    const float y = d * rsqrtf(var + 1e-5f) * gg + be2;
    Out[((size_t)h * NS_ + row0 + r) * ENC_ + lane] = gelu_exact(y);
  }
}

// ---------------- ctx = mean_n(h2), plus temperature clip ----------------
__global__ __launch_bounds__(256) void ctx_kernel(
    const float* __restrict__ h2, const float* __restrict__ temperature,
    float* __restrict__ ctx, float* __restrict__ tmp)
{
  __shared__ float red[256];
  const int h = blockIdx.x;
  const int e = threadIdx.x & 63, part = threadIdx.x >> 6;
  float s = 0.f;
  for (int n = part; n < NS_; n += 4) s += h2[((size_t)h * NS_ + n) * ENC_ + e];
  red[threadIdx.x] = s;
  __syncthreads();
  if (part == 0) {
    const float tot = s + red[64 + e] + red[128 + e] + red[192 + e];
    ctx[h * ENC_ + e] = tot * (1.f / NS_);
  }
  if (h == 0 && threadIdx.x == 0) {
    const float t = fminf(fmaxf(temperature[0], 0.1f), 2.0f);
    tmp[0] = t; tmp[1] = 1.f / t;
  }
}

// ---------------- p = gelu(LN(ctx @ pg_w1 + pg_b1)) ----------------
__global__ __launch_bounds__(128) void pvec_kernel(
    const float* __restrict__ ctx, const float* __restrict__ w1,
    const float* __restrict__ b1, const float* __restrict__ g,
    const float* __restrict__ b, float* __restrict__ pvec)
{
  const int h = blockIdx.x, j = threadIdx.x;
  float acc = b1[h * FEAT_ + j];
  #pragma unroll 4
  for (int e = 0; e < ENC_; ++e)
    acc = fmaf(ctx[h * ENC_ + e], w1[((size_t)h * ENC_ + e) * FEAT_ + j], acc);
  __shared__ float sred[2];
  const int lane = j & 63, wv = j >> 6;
  float ps = wave_sum(acc);
  if (lane == 0) sred[wv] = ps;
  __syncthreads();
  const float m = (sred[0] + sred[1]) * (1.f / FEAT_);
  const float d = acc - m;
  const float vs = wave_sum(d * d);
  __syncthreads();
  if (lane == 0) sred[wv] = vs;
  __syncthreads();
  const float var = (sred[0] + sred[1]) * (1.f / FEAT_);
  const float y = d * rsqrtf(var + 1e-5f) * g[h * FEAT_ + j] + b[h * FEAT_ + j];
  pvec[h * FEAT_ + j] = gelu_exact(y);
}

// ---------------- zero the pad row (i=15) of the W bf16 image ----------------
__global__ __launch_bounds__(256) void zero_pad_kernel(char* __restrict__ WbfB)
{
  const int g = blockIdx.x, tid = threadIdx.x;
  if (tid < 128) {
    *(unsigned*)(WbfB + (size_t)g * WGB_ + 15*512 + tid*4) = 0u;
    *(unsigned*)(WbfB + (size_t)g * WGB_ + 8192 + 15*512 + tid*4) = 0u;
  }
}

// ---------------- params = tanh(p @ pg_w2 + pg_b2)*2 → W bf16 hi/lo image + sb/leaf/tree ----------------
__global__ __launch_bounds__(256) void params_kernel(
    const float* __restrict__ pvec, const float* __restrict__ w2,
    const float* __restrict__ b2, const float* __restrict__ tmp,
    char* __restrict__ WbfB, float* __restrict__ sbv,
    float* __restrict__ lraw, float* __restrict__ traw)
{
  __shared__ float pl[FEAT_];
  const int h = blockIdx.y;
  if (threadIdx.x < FEAT_) pl[threadIdx.x] = pvec[h * FEAT_ + threadIdx.x];
  __syncthreads();
  const int j4 = blockIdx.x * 1024 + threadIdx.x * 4;
  if (j4 >= P_) return;
  const float it = tmp[1];
  float4 acc = *reinterpret_cast<const float4*>(b2 + (size_t)h * P_ + j4);
  const float* __restrict__ wp = w2 + (size_t)h * FEAT_ * P_ + j4;
  #pragma unroll 4
  for (int k = 0; k < FEAT_; ++k) {
    const float pk = pl[k];
    const float4 wv = *reinterpret_cast<const float4*>(wp + (size_t)k * P_);
    acc.x = fmaf(pk, wv.x, acc.x);
    acc.y = fmaf(pk, wv.y, acc.y);
    acc.z = fmaf(pk, wv.z, acc.z);
    acc.w = fmaf(pk, wv.w, acc.w);
  }
  const float vals[4] = {acc.x, acc.y, acc.z, acc.w};
  if (j4 < SW_) {
    const int t = j4 / 3840, rem = j4 - t * 3840, i = rem >> 8, d = rem & 255;
    const int g = h * T_ + t;
    ushort4_t hs, ls;
    #pragma unroll
    for (int q = 0; q < 4; ++q) {
      const float v = tanhf(vals[q]) * 2.f * it;
      const unsigned short hb = f2bf(v);
      hs[q] = hb;
      ls[q] = f2bf(v - bf2f(hb));
    }
    const unsigned off = (unsigned)(i * 512 + d * 2) ^ ((unsigned)(i & 7) << 4);
    char* base = WbfB + (size_t)g * WGB_;
    *(ushort4_t*)(base + off) = hs;
    *(ushort4_t*)(base + 8192 + off) = ls;
  } else {
    #pragma unroll
    for (int q = 0; q < 4; ++q) {
      const int j = j4 + q;
      const float v = tanhf(vals[q]) * 2.f;
      if (j < SW_ + SB_)            sbv[h * SB_ + (j - SW_)] = v * it;
      else if (j < SW_ + SB_ + LF_) lraw[h * LF_ + (j - SW_ - SB_)] = v;
      else                          traw[h * T_ + (j - SW_ - SB_ - LF_)] = v;
    }
  }
}

// ---------------- head/tree softmax, scaled leaf probs + slA MFMA A-image ----------------
__global__ __launch_bounds__(256) void finalize_kernel(
    const float* __restrict__ head_weights, const float* __restrict__ traw,
    const float* __restrict__ lraw, const float* __restrict__ tmp,
    float* __restrict__ sl, char* __restrict__ slA)
{
  __shared__ float hw[H_];
  __shared__ float wt[H_ * T_];
  const int tid = threadIdx.x;
  if (tid == 0) {
    float m = -1e30f;
    for (int h = 0; h < H_; ++h) m = fmaxf(m, head_weights[h]);
    float s = 0.f, e[H_];
    for (int h = 0; h < H_; ++h) { e[h] = __expf(head_weights[h] - m); s += e[h]; }
    for (int h = 0; h < H_; ++h) hw[h] = e[h] / s;
  }
  __syncthreads();
  if (tid < H_ * T_) {
    const int h = tid / T_;
    float m = -1e30f;
    for (int t = 0; t < T_; ++t) m = fmaxf(m, traw[h * T_ + t]);
    float s = 0.f;
    for (int t = 0; t < T_; ++t) s += __expf(traw[h * T_ + t] - m);
    wt[tid] = hw[h] * __expf(traw[tid] - m) / s;
  }
  __syncthreads();
  const float it = tmp[1];
  for (int row = tid; row < H_ * T_ * L_; row += 256) {   // row = g*16 + l
    const int ht = row >> 4;
    const float* __restrict__ lr = lraw + (size_t)row * C_;
    float m = -1e30f;
    #pragma unroll
    for (int c = 0; c < C_; ++c) m = fmaxf(m, lr[c]);
    float e[C_]; float s = 0.f;
    #pragma unroll
    for (int c = 0; c < C_; ++c) { e[c] = __expf((lr[c] - m) * it); s += e[c]; }
    const float sc = wt[ht] / s;
    #pragma unroll
    for (int c = 0; c < C_; ++c) sl[(size_t)row * C_ + c] = e[c] * sc;
  }
  __syncthreads();
  // pack slA[g][lane]: A-fragment image for mfma_f32_16x16x32_bf16:
  // lane p: row c = p&15, k = (p>>4)*8 + j; value = sl[g*16 + l][c] for l=k<16 else 0
  for (int idx = tid; idx < G_ * 64; idx += 256) {
    const int g = idx >> 6, p = idx & 63;
    const int c = p & 15, kg = p >> 4;
    ushort4_t w0, w1;
    #pragma unroll
    for (int j = 0; j < 8; ++j) {
      const int l = kg * 8 + j;
      const unsigned short v = (l < 16 && c < 10) ? f2bf(sl[(size_t)(g * 16 + l) * C_ + c]) : (unsigned short)0;
      if (j < 4) w0[j] = v; else w1[j - 4] = v;
    }
    *(ushort4_t*)(slA + (size_t)idx * 16) = w0;
    *(ushort4_t*)(slA + (size_t)idx * 16 + 8) = w1;
  }
}

// ---------------- fused MFMA query kernel (gchunk-split, MFMA leaf mixture) ----------------
__global__ __launch_bounds__(256, 3) void qk_kernel(
    const float* __restrict__ Xq, const char* __restrict__ WbfB,
    const char* __restrict__ slA, const float* __restrict__ sbv,
    float* __restrict__ outP)
{
  __shared__ char lds[40960];       // [0,32768): W dbuf (2x16KB); [32768,40960): 4x2KB tw
  const int tid  = threadIdx.x;
  const int lane = tid & 63;
  const int wv   = tid >> 6;
  const int n0   = blockIdx.x * 128;
  const int g0   = blockIdx.y * GC_;
  const int lrow = lane & 15;
  const int lkg  = lane >> 4;

  // ---- build A-fragments (queries) in registers (hi/lo bf16) ----
  short8 Ah[2][8], Al[2][8];
  #pragma unroll
  for (int rt = 0; rt < 2; ++rt) {
    const float* xr = Xq + (size_t)(n0 + wv * 32 + rt * 16 + lrow) * 256 + lkg * 8;
    #pragma unroll
    for (int ks = 0; ks < 8; ++ks) {
      const f32x4 a = *(const f32x4*)(xr + ks * 32);
      const f32x4 b = *(const f32x4*)(xr + ks * 32 + 4);
      short8 hh, ll;
      #pragma unroll
      for (int j = 0; j < 4; ++j) {
        unsigned short hb = f2bf(a[j]);
        hh[j] = (short)hb; ll[j] = (short)f2bf(a[j] - bf2f(hb));
        hb = f2bf(b[j]);
        hh[4 + j] = (short)hb; ll[4 + j] = (short)f2bf(b[j] - bf2f(hb));
      }
      Ah[rt][ks] = hh; Al[rt][ks] = ll;
    }
  }

  // ---- prologue: stage group g0 ----
  {
    const char* src = WbfB + (size_t)g0 * WGB_;
    #pragma unroll
    for (int it = 0; it < 4; ++it) {
      const int off = it * 4096 + tid * 16;
      *(f32x4*)(lds + off) = *(const f32x4*)(src + off);
    }
  }
  __syncthreads();

  char* tw = lds + 32768 + wv * 2048;
  const int q  = (lane & 15) + ((lane & 32) >> 1);   // query owned for tree (0..31)
  const int h  = (lane >> 4) & 1;                    // leaf half owned
  const bool lo32 = (lane < 32);

  f32x4 Cac0 = {0.f,0.f,0.f,0.f}, Cac1 = {0.f,0.f,0.f,0.f};

  int cur = 0;
  for (int gi = 0; gi < GC_; ++gi) {
    const int g = g0 + gi;
    if (gi + 1 < GC_) {             // stage next group into the other buffer
      const char* src = WbfB + (size_t)(g + 1) * WGB_;
      char* dst = lds + (cur ^ 1) * WGB_;
      #pragma unroll
      for (int it = 0; it < 4; ++it) {
        const int off = it * 4096 + tid * 16;
        *(f32x4*)(dst + off) = *(const f32x4*)(src + off);
      }
    }
    const char* bb = lds + cur * WGB_;
    f32x4 Ch[2], Cm[2];
    #pragma unroll
    for (int rt = 0; rt < 2; ++rt) { Ch[rt] = (f32x4){0,0,0,0}; Cm[rt] = (f32x4){0,0,0,0}; }
    #pragma unroll
    for (int ks = 0; ks < 8; ++ks) {
      const unsigned adr = (unsigned)(lrow * 512 + ks * 64 + lkg * 16) ^ ((unsigned)(lrow & 7) << 4);
      const short8 bh = *(const short8*)(bb + adr);
      const short8 bl = *(const short8*)(bb + 8192 + adr);
      #pragma unroll
      for (int rt = 0; rt < 2; ++rt) {
        Ch[rt] = __builtin_amdgcn_mfma_f32_16x16x32_bf16(Ah[rt][ks], bh, Ch[rt], 0, 0, 0);
        Cm[rt] = __builtin_amdgcn_mfma_f32_16x16x32_bf16(Ah[rt][ks], bl, Cm[rt], 0, 0, 0);
        Cm[rt] = __builtin_amdgcn_mfma_f32_16x16x32_bf16(Al[rt][ks], bh, Cm[rt], 0, 0, 0);
      }
    }
    // transpose logits through per-wave LDS: [16 i][32 q] f32, swizzled
    #pragma unroll
    for (int rt = 0; rt < 2; ++rt) {
      f32x4 cs;
      #pragma unroll
      for (int r = 0; r < 4; ++r) cs[r] = Ch[rt][r] + Cm[rt][r];
      const unsigned a = (unsigned)(lrow * 128 + (rt * 16 + lkg * 4) * 4) ^ ((unsigned)(lrow & 7) << 4);
      *(f32x4*)(tw + a) = cs;
    }
    // per-lane: 15 logits of query q -> sigmoid -> tree -> 8 leaves (half h)
    float dec[15];
    #pragma unroll
    for (int c = 0; c < 15; ++c) {
      const unsigned a = (unsigned)(c * 128 + q * 4) ^ ((unsigned)(c & 7) << 4);
      const float lg = *(const float*)(tw + a) + sbv[g * 15 + c];
      dec[c] = 1.f / (1.f + __expf(-lg));
    }
    float a_[2], b_[4], c_[8], r8[8];
    a_[0] = 1.f - dec[0]; a_[1] = dec[0];
    #pragma unroll
    for (int j = 0; j < 2; ++j) { b_[2*j] = a_[j] * (1.f - dec[1+j]); b_[2*j+1] = a_[j] * dec[1+j]; }
    #pragma unroll
    for (int j = 0; j < 4; ++j) { c_[2*j] = b_[j] * (1.f - dec[3+j]); c_[2*j+1] = b_[j] * dec[3+j]; }
    #pragma unroll
    for (int j = 0; j < 4; ++j) {
      const int nd = h * 4 + j;
      r8[2*j]   = c_[nd] * (1.f - dec[7+nd]);
      r8[2*j+1] = c_[nd] * dec[7+nd];
    }
    // pack reach to bf16 pairs, build B-frags (tile0 = self, tile1 = xor32)
    const unsigned P0 = cvt_pk_bf16(r8[0], r8[1]);
    const unsigned P1 = cvt_pk_bf16(r8[2], r8[3]);
    const unsigned P2 = cvt_pk_bf16(r8[4], r8[5]);
    const unsigned P3 = cvt_pk_bf16(r8[6], r8[7]);
    const unsigned E0 = __shfl_xor(P0, 32, 64);
    const unsigned E1 = __shfl_xor(P1, 32, 64);
    const unsigned E2 = __shfl_xor(P2, 32, 64);
    const unsigned E3 = __shfl_xor(P3, 32, 64);
    uint4_t b0u = { lo32 ? P0 : 0u, lo32 ? P1 : 0u, lo32 ? P2 : 0u, lo32 ? P3 : 0u };
    uint4_t b1u = { lo32 ? E0 : 0u, lo32 ? E1 : 0u, lo32 ? E2 : 0u, lo32 ? E3 : 0u };
    const short8 B0 = __builtin_bit_cast(short8, b0u);
    const short8 B1 = __builtin_bit_cast(short8, b1u);
    const short8 Asl = *(const short8*)(slA + (size_t)g * 1024 + lane * 16);
    Cac0 = __builtin_amdgcn_mfma_f32_16x16x32_bf16(Asl, B0, Cac0, 0, 0, 0);
    Cac1 = __builtin_amdgcn_mfma_f32_16x16x32_bf16(Asl, B1, Cac1, 0, 0, 0);
    __syncthreads();
    cur ^= 1;
  }

  // store partial: D[c, q'] col=lane&15=q', row c=(lane>>4)*4+reg
  float* base = outP + (size_t)blockIdx.y * ((size_t)NQ_ * 10);
  const int qcol = lane & 15;
  const int cb   = (lane >> 4) * 4;
  #pragma unroll
  for (int j = 0; j < 4; ++j) {
    const int c = cb + j;
    if (c < 10) {
      base[(size_t)(n0 + wv * 32 + qcol) * 10 + c]      = Cac0[j];
      base[(size_t)(n0 + wv * 32 + 16 + qcol) * 10 + c] = Cac1[j];
    }
  }
}

// ---------------- sum the 3 gchunk partials ----------------
__global__ __launch_bounds__(256) void reduce_kernel(const float* __restrict__ p, float* __restrict__ out)
{
  const size_t i = ((size_t)blockIdx.x * 256 + threadIdx.x) * 4;
  const f32x4 a = *(const f32x4*)(p + i);
  const f32x4 b = *(const f32x4*)(p + (size_t)NQ_ * 10 + i);
  const f32x4 c = *(const f32x4*)(p + (size_t)2 * NQ_ * 10 + i);
  f32x4 s;
  #pragma unroll
  for (int j = 0; j < 4; ++j) s[j] = a[j] + b[j] + c[j];
  *(f32x4*)(out + i) = s;
}

// ---------------- diagnostic marker: only runs if a launch failed ----------------
__global__ void mark_kernel(float* out, float v) { out[threadIdx.x] = v; }

extern "C" void kernel_launch(void* const* d_in, const int* in_sizes, int n_in,
                              void* d_out, int out_size, void* d_ws, size_t ws_size,
                              hipStream_t stream) {
  (void)in_sizes; (void)n_in; (void)out_size;
  const float* Xs          = (const float*)d_in[0];
  const float* Xq          = (const float*)d_in[1];
  const float* enc_w1      = (const float*)d_in[2];
  const float* enc_b1      = (const float*)d_in[3];
  const float* ln1_g       = (const float*)d_in[4];
  const float* ln1_b       = (const float*)d_in[5];
  const float* enc_w2      = (const float*)d_in[6];
  const float* enc_b2      = (const float*)d_in[7];
  const float* ln2_g       = (const float*)d_in[8];
  const float* ln2_b       = (const float*)d_in[9];
  const float* pg_w1       = (const float*)d_in[10];
  const float* pg_b1       = (const float*)d_in[11];
  const float* pg_ln_g     = (const float*)d_in[12];
  const float* pg_ln_b     = (const float*)d_in[13];
  const float* pg_w2       = (const float*)d_in[14];
  const float* pg_b2       = (const float*)d_in[15];
  const float* head_wts    = (const float*)d_in[16];
  const float* temperature = (const float*)d_in[17];

  float* ws   = (float*)d_ws;
  float* h1   = ws + OFF_H1;
  float* h2   = ws + OFF_H2;
  float* ctx  = ws + OFF_CTX;
  float* pvec = ws + OFF_PVEC;
  float* tmp  = ws + OFF_TMP;
  float* sbp  = ws + OFF_SB;
  float* lrw  = ws + OFF_LRAW;
  float* trw  = ws + OFF_TRAW;
  float* slp  = ws + OFF_SL;
  char*  wbf  = (char*)(ws + OFF_WBF);
  char*  slA  = (char*)(ws + OFF_SLA);
  float* outP = ws + OFF_OUTP;
  float* outp = (float*)d_out;

  unsigned mask = 0;
  (void)hipGetLastError();
  if (ws_size < WS_NEED_FLOATS * sizeof(float)) mask |= 0x80u;

  if (!mask) {
    zero_pad_kernel<<<G_, 256, 0, stream>>>(wbf);
    if (hipGetLastError() != hipSuccess) mask |= 1u;
    enc1_kernel<<<dim3(128, 5), 256, 0, stream>>>(Xs, enc_w1, enc_b1, ln1_g, ln1_b, h1);
    if (hipGetLastError() != hipSuccess) mask |= 1u;
    enc2_kernel<<<dim3(128, 5), 256, 0, stream>>>(h1, enc_w2, enc_b2, ln2_g, ln2_b, h2);
    if (hipGetLastError() != hipSuccess) mask |= 2u;
    ctx_kernel<<<5, 256, 0, stream>>>(h2, temperature, ctx, tmp);
    if (hipGetLastError() != hipSuccess) mask |= 4u;
    pvec_kernel<<<5, 128, 0, stream>>>(ctx, pg_w1, pg_b1, pg_ln_g, pg_ln_b, pvec);
    if (hipGetLastError() != hipSuccess) mask |= 8u;
    params_kernel<<<dim3(59, 5), 256, 0, stream>>>(pvec, pg_w2, pg_b2, tmp, wbf, sbp, lrw, trw);
    if (hipGetLastError() != hipSuccess) mask |= 16u;
    finalize_kernel<<<1, 256, 0, stream>>>(head_wts, trw, lrw, tmp, slp, slA);
    if (hipGetLastError() != hipSuccess) mask |= 32u;
    qk_kernel<<<dim3(NQ_ / 128, 3), 256, 0, stream>>>(Xq, wbf, slA, sbp, outP);
    if (hipGetLastError() != hipSuccess) mask |= 64u;
    reduce_kernel<<<(NQ_ * 10) / (256 * 4), 256, 0, stream>>>(outP, outp);
    if (hipGetLastError() != hipSuccess) mask |= 64u;
  }
  if (mask) {
    mark_kernel<<<1, 16, 0, stream>>>(outp, 1024.f + 4.f * (float)mask);
    (void)hipGetLastError();
  }
}

// Round 6
// 379.954 us; speedup vs baseline: 1.3558x; 1.3558x over previous
//
#include <hip/hip_runtime.h>

#define DEV __device__ __forceinline__

typedef __attribute__((ext_vector_type(8))) short short8;
typedef __attribute__((ext_vector_type(4))) float f32x4;
typedef __attribute__((ext_vector_type(4))) unsigned short ushort4_t;
typedef __attribute__((ext_vector_type(4))) unsigned int uint4_t;

namespace {
constexpr int D_ = 256, C_ = 10, T_ = 15, H_ = 5, ENC_ = 64, L_ = 16;
constexpr int NS_ = 2048, NQ_ = 32768;
constexpr int P_ = 60240, SW_ = 57600, SB_ = 225, LF_ = 2400;
constexpr int FEAT_ = 128;
constexpr int G_ = 75;                      // H*T groups
constexpr int WGB_ = 16384;                 // bytes per group W-image

// workspace layout (in floats)
constexpr size_t OFF_H1   = 0;
constexpr size_t OFF_H2   = OFF_H1 + (size_t)H_*NS_*ENC_;
constexpr size_t OFF_CTX  = OFF_H2 + (size_t)H_*NS_*ENC_;
constexpr size_t OFF_PVEC = OFF_CTX + (size_t)H_*ENC_;
constexpr size_t OFF_TMP  = OFF_PVEC + (size_t)H_*FEAT_;
constexpr size_t OFF_SB   = OFF_TMP + 8;
constexpr size_t OFF_LRAW = OFF_SB + (size_t)H_*T_*T_;
constexpr size_t OFF_TRAW = OFF_LRAW + (size_t)H_*T_*L_*C_;
constexpr size_t OFF_SL   = OFF_TRAW + (size_t)H_*T_;
constexpr size_t OFF_WBF  = OFF_SL + (size_t)H_*T_*L_*C_;       // 75*16384B
constexpr size_t OFF_SLA  = OFF_WBF + (size_t)G_*WGB_/4;        // 75*1024B
constexpr size_t WS_NEED_FLOATS = OFF_SLA + (size_t)G_*1024/4;
} // namespace

DEV float wave_sum(float v) {
  #pragma unroll
  for (int o = 32; o; o >>= 1) v += __shfl_xor(v, o, 64);
  return v;
}
DEV float gelu_exact(float x) { return 0.5f * x * (1.f + erff(x * 0.70710678118654752f)); }
DEV unsigned short f2bf(float x) {            // RNE bf16
  unsigned u = __float_as_uint(x);
  return (unsigned short)((u + 0x7FFFu + ((u >> 16) & 1u)) >> 16);
}
DEV float bf2f(unsigned short b) { return __uint_as_float(((unsigned)b) << 16); }
DEV unsigned cvt_pk_bf16(float lo, float hi) {
  unsigned d;
  asm("v_cvt_pk_bf16_f32 %0, %1, %2" : "=v"(d) : "v"(lo), "v"(hi));
  return d;
}
// async global -> LDS DMA, 16B per lane; lds dest = uniform base + lane*16
DEV void gload16(const char* g, char* l) {
  __builtin_amdgcn_global_load_lds(
      (const __attribute__((address_space(1))) void*)g,
      (__attribute__((address_space(3))) void*)l, 16, 0, 0);
}

// ---------------- encoder: h = gelu(LN(X @ W + b)), one wave per 4 rows ----------------
__global__ __launch_bounds__(256) void enc1_kernel(
    const float* __restrict__ Xbase,
    const float* __restrict__ W, const float* __restrict__ bias,
    const float* __restrict__ gam, const float* __restrict__ bet,
    float* __restrict__ Out)
{
  constexpr int K = 256;
  const int h = blockIdx.y;
  const int lane = threadIdx.x & 63;
  const int wv = threadIdx.x >> 6;
  const int row0 = blockIdx.x * 16 + wv * 4;
  const float* __restrict__ X = Xbase + (size_t)row0 * K;
  const float* __restrict__ wc = W + (size_t)h * K * ENC_ + lane;
  float a0 = 0.f, a1 = 0.f, a2 = 0.f, a3 = 0.f;
  #pragma unroll 4
  for (int k = 0; k < K; ++k) {
    const float wkl = wc[(size_t)k * ENC_];
    a0 = fmaf(X[k],       wkl, a0);
    a1 = fmaf(X[K + k],   wkl, a1);
    a2 = fmaf(X[2*K + k], wkl, a2);
    a3 = fmaf(X[3*K + k], wkl, a3);
  }
  const float bb = bias[h*ENC_ + lane];
  const float gg = gam[h*ENC_ + lane], be2 = bet[h*ENC_ + lane];
  float acc[4] = {a0 + bb, a1 + bb, a2 + bb, a3 + bb};
  #pragma unroll
  for (int r = 0; r < 4; ++r) {
    const float m = wave_sum(acc[r]) * (1.f / ENC_);
    const float d = acc[r] - m;
    const float var = wave_sum(d * d) * (1.f / ENC_);
    const float y = d * rsqrtf(var + 1e-5f) * gg + be2;
    Out[((size_t)h * NS_ + row0 + r) * ENC_ + lane] = gelu_exact(y);
  }
}

__global__ __launch_bounds__(256) void enc2_kernel(
    const float* __restrict__ Xbase,
    const float* __restrict__ W, const float* __restrict__ bias,
    const float* __restrict__ gam, const float* __restrict__ bet,
    float* __restrict__ Out)
{
  constexpr int K = 64;
  const int h = blockIdx.y;
  const int lane = threadIdx.x & 63;
  const int wv = threadIdx.x >> 6;
  const int row0 = blockIdx.x * 16 + wv * 4;
  const float* __restrict__ X = Xbase + (size_t)h * NS_ * ENC_ + (size_t)row0 * K;
  const float* __restrict__ wc = W + (size_t)h * K * ENC_ + lane;
  float a0 = 0.f, a1 = 0.f, a2 = 0.f, a3 = 0.f;
  #pragma unroll 4
  for (int k = 0; k < K; ++k) {
    const float wkl = wc[(size_t)k * ENC_];
    a0 = fmaf(X[k],       wkl, a0);
    a1 = fmaf(X[K + k],   wkl, a1);
    a2 = fmaf(X[2*K + k], wkl, a2);
    a3 = fmaf(X[3*K + k], wkl, a3);
  }
  const float bb = bias[h*ENC_ + lane];
  const float gg = gam[h*ENC_ + lane], be2 = bet[h*ENC_ + lane];
  float acc[4] = {a0 + bb, a1 + bb, a2 + bb, a3 + bb};
  #pragma unroll
  for (int r = 0; r < 4; ++r) {
    const float m = wave_sum(acc[r]) * (1.f / ENC_);
    const float d = acc[r] - m;
    const float var = wave_sum(d * d) * (1.f / ENC_);
    const float y = d * rsqrtf(var + 1e-5f) * gg + be2;
    Out[((size_t)h * NS_ + row0 + r) * ENC_ + lane] = gelu_exact(y);
  }
}

// ---------------- ctx = mean_n(h2), plus temperature clip ----------------
__global__ __launch_bounds__(256) void ctx_kernel(
    const float* __restrict__ h2, const float* __restrict__ temperature,
    float* __restrict__ ctx, float* __restrict__ tmp)
{
  __shared__ float red[256];
  const int h = blockIdx.x;
  const int e = threadIdx.x & 63, part = threadIdx.x >> 6;
  float s = 0.f;
  for (int n = part; n < NS_; n += 4) s += h2[((size_t)h * NS_ + n) * ENC_ + e];
  red[threadIdx.x] = s;
  __syncthreads();
  if (part == 0) {
    const float tot = s + red[64 + e] + red[128 + e] + red[192 + e];
    ctx[h * ENC_ + e] = tot * (1.f / NS_);
  }
  if (h == 0 && threadIdx.x == 0) {
    const float t = fminf(fmaxf(temperature[0], 0.1f), 2.0f);
    tmp[0] = t; tmp[1] = 1.f / t;
  }
}

// ---------------- p = gelu(LN(ctx @ pg_w1 + pg_b1)) ----------------
__global__ __launch_bounds__(128) void pvec_kernel(
    const float* __restrict__ ctx, const float* __restrict__ w1,
    const float* __restrict__ b1, const float* __restrict__ g,
    const float* __restrict__ b, float* __restrict__ pvec)
{
  const int h = blockIdx.x, j = threadIdx.x;
  float acc = b1[h * FEAT_ + j];
  #pragma unroll 4
  for (int e = 0; e < ENC_; ++e)
    acc = fmaf(ctx[h * ENC_ + e], w1[((size_t)h * ENC_ + e) * FEAT_ + j], acc);
  __shared__ float sred[2];
  const int lane = j & 63, wv = j >> 6;
  float ps = wave_sum(acc);
  if (lane == 0) sred[wv] = ps;
  __syncthreads();
  const float m = (sred[0] + sred[1]) * (1.f / FEAT_);
  const float d = acc - m;
  const float vs = wave_sum(d * d);
  __syncthreads();
  if (lane == 0) sred[wv] = vs;
  __syncthreads();
  const float var = (sred[0] + sred[1]) * (1.f / FEAT_);
  const float y = d * rsqrtf(var + 1e-5f) * g[h * FEAT_ + j] + b[h * FEAT_ + j];
  pvec[h * FEAT_ + j] = gelu_exact(y);
}

// ---------------- zero the pad row (i=15) of the W bf16 image ----------------
// (row-15 swizzle XORs bytes only within the row, so linear zeroing covers it)
__global__ __launch_bounds__(256) void zero_pad_kernel(char* __restrict__ WbfB)
{
  const int g = blockIdx.x, tid = threadIdx.x;
  if (tid < 128) {
    *(unsigned*)(WbfB + (size_t)g * WGB_ + 15*512 + tid*4) = 0u;
    *(unsigned*)(WbfB + (size_t)g * WGB_ + 8192 + 15*512 + tid*4) = 0u;
  }
}

// ---------------- params = tanh(p @ pg_w2 + pg_b2)*2 → W bf16 hi/lo image + sb/leaf/tree ----------------
__global__ __launch_bounds__(256) void params_kernel(
    const float* __restrict__ pvec, const float* __restrict__ w2,
    const float* __restrict__ b2, const float* __restrict__ tmp,
    char* __restrict__ WbfB, float* __restrict__ sbv,
    float* __restrict__ lraw, float* __restrict__ traw)
{
  __shared__ float pl[FEAT_];
  const int h = blockIdx.y;
  if (threadIdx.x < FEAT_) pl[threadIdx.x] = pvec[h * FEAT_ + threadIdx.x];
  __syncthreads();
  const int j4 = blockIdx.x * 1024 + threadIdx.x * 4;
  if (j4 >= P_) return;
  const float it = tmp[1];
  float4 acc = *reinterpret_cast<const float4*>(b2 + (size_t)h * P_ + j4);
  const float* __restrict__ wp = w2 + (size_t)h * FEAT_ * P_ + j4;
  #pragma unroll 4
  for (int k = 0; k < FEAT_; ++k) {
    const float pk = pl[k];
    const float4 wv = *reinterpret_cast<const float4*>(wp + (size_t)k * P_);
    acc.x = fmaf(pk, wv.x, acc.x);
    acc.y = fmaf(pk, wv.y, acc.y);
    acc.z = fmaf(pk, wv.z, acc.z);
    acc.w = fmaf(pk, wv.w, acc.w);
  }
  const float vals[4] = {acc.x, acc.y, acc.z, acc.w};
  if (j4 < SW_) {
    const int t = j4 / 3840, rem = j4 - t * 3840, i = rem >> 8, d = rem & 255;
    const int g = h * T_ + t;
    ushort4_t hs, ls;
    #pragma unroll
    for (int q = 0; q < 4; ++q) {
      const float v = tanhf(vals[q]) * 2.f * it;
      const unsigned short hb = f2bf(v);
      hs[q] = hb;
      ls[q] = f2bf(v - bf2f(hb));
    }
    const unsigned off = (unsigned)(i * 512 + d * 2) ^ ((unsigned)(i & 15) << 4);
    char* base = WbfB + (size_t)g * WGB_;
    *(ushort4_t*)(base + off) = hs;
    *(ushort4_t*)(base + 8192 + off) = ls;
  } else {
    #pragma unroll
    for (int q = 0; q < 4; ++q) {
      const int j = j4 + q;
      const float v = tanhf(vals[q]) * 2.f;
      if (j < SW_ + SB_)            sbv[h * SB_ + (j - SW_)] = v * it;
      else if (j < SW_ + SB_ + LF_) lraw[h * LF_ + (j - SW_ - SB_)] = v;
      else                          traw[h * T_ + (j - SW_ - SB_ - LF_)] = v;
    }
  }
}

// ---------------- head/tree softmax, scaled leaf probs + slA MFMA A-image ----------------
__global__ __launch_bounds__(256) void finalize_kernel(
    const float* __restrict__ head_weights, const float* __restrict__ traw,
    const float* __restrict__ lraw, const float* __restrict__ tmp,
    float* __restrict__ sl, char* __restrict__ slA)
{
  __shared__ float hw[H_];
  __shared__ float wt[H_ * T_];
  const int tid = threadIdx.x;
  if (tid == 0) {
    float m = -1e30f;
    for (int h = 0; h < H_; ++h) m = fmaxf(m, head_weights[h]);
    float s = 0.f, e[H_];
    for (int h = 0; h < H_; ++h) { e[h] = __expf(head_weights[h] - m); s += e[h]; }
    for (int h = 0; h < H_; ++h) hw[h] = e[h] / s;
  }
  __syncthreads();
  if (tid < H_ * T_) {
    const int h = tid / T_;
    float m = -1e30f;
    for (int t = 0; t < T_; ++t) m = fmaxf(m, traw[h * T_ + t]);
    float s = 0.f;
    for (int t = 0; t < T_; ++t) s += __expf(traw[h * T_ + t] - m);
    wt[tid] = hw[h] * __expf(traw[tid] - m) / s;
  }
  __syncthreads();
  const float it = tmp[1];
  for (int row = tid; row < H_ * T_ * L_; row += 256) {   // row = g*16 + l
    const int ht = row >> 4;
    const float* __restrict__ lr = lraw + (size_t)row * C_;
    float m = -1e30f;
    #pragma unroll
    for (int c = 0; c < C_; ++c) m = fmaxf(m, lr[c]);
    float e[C_]; float s = 0.f;
    #pragma unroll
    for (int c = 0; c < C_; ++c) { e[c] = __expf((lr[c] - m) * it); s += e[c]; }
    const float sc = wt[ht] / s;
    #pragma unroll
    for (int c = 0; c < C_; ++c) sl[(size_t)row * C_ + c] = e[c] * sc;
  }
  __syncthreads();
  // pack slA[g][lane]: A-fragment image for mfma_f32_16x16x32_bf16:
  // lane p: row c = p&15, k = (p>>4)*8 + j; value = sl[g*16 + l][c] for l=k<16 else 0
  for (int idx = tid; idx < G_ * 64; idx += 256) {
    const int g = idx >> 6, p = idx & 63;
    const int c = p & 15, kg = p >> 4;
    ushort4_t w0, w1;
    #pragma unroll
    for (int j = 0; j < 8; ++j) {
      const int l = kg * 8 + j;
      const unsigned short v = (l < 16 && c < 10) ? f2bf(sl[(size_t)(g * 16 + l) * C_ + c]) : (unsigned short)0;
      if (j < 4) w0[j] = v; else w1[j - 4] = v;
    }
    *(ushort4_t*)(slA + (size_t)idx * 16) = w0;
    *(ushort4_t*)(slA + (size_t)idx * 16 + 8) = w1;
  }
}

// ---------------- fused MFMA query kernel (single chunk, async DMA staging) ----------------
// 128 queries/block (4 waves x 32q = 2 row-tiles of 16), grid = 256 = 1 block/CU.
// 2-phase: issue global_load_lds DMA for group g+1, compute group g, one barrier.
__global__ __launch_bounds__(256) void qk_kernel(
    const float* __restrict__ Xq, const char* __restrict__ WbfB,
    const char* __restrict__ slA, const float* __restrict__ sbv,
    float* __restrict__ out)
{
  __shared__ char lds[40960];       // [0,32768): W dbuf (2x16KB); [32768,40960): 4x2KB tw
  const int tid  = threadIdx.x;
  const int lane = tid & 63;
  const int wv   = tid >> 6;
  const int n0   = blockIdx.x * 128;
  const int lrow = lane & 15;
  const int lkg  = lane >> 4;

  // ---- build A-fragments (queries) in registers (hi/lo bf16) ----
  short8 Ah[2][8], Al[2][8];
  #pragma unroll
  for (int rt = 0; rt < 2; ++rt) {
    const float* xr = Xq + (size_t)(n0 + wv * 32 + rt * 16 + lrow) * 256 + lkg * 8;
    #pragma unroll
    for (int ks = 0; ks < 8; ++ks) {
      const f32x4 a = *(const f32x4*)(xr + ks * 32);
      const f32x4 b = *(const f32x4*)(xr + ks * 32 + 4);
      short8 hh, ll;
      #pragma unroll
      for (int j = 0; j < 4; ++j) {
        unsigned short hb = f2bf(a[j]);
        hh[j] = (short)hb; ll[j] = (short)f2bf(a[j] - bf2f(hb));
        hb = f2bf(b[j]);
        hh[4 + j] = (short)hb; ll[4 + j] = (short)f2bf(b[j] - bf2f(hb));
      }
      Ah[rt][ks] = hh; Al[rt][ks] = ll;
    }
  }

  // ---- prologue: DMA group 0 into buf0 (each wave copies its 4KB segment) ----
  #pragma unroll
  for (int it = 0; it < 4; ++it) {
    const int seg = wv * 4096 + it * 1024;
    gload16(WbfB + seg + lane * 16, lds + seg);
  }
  __syncthreads();                  // drains vmcnt -> buf0 ready

  char* tw = lds + 32768 + wv * 2048;
  const int q  = (lane & 15) + ((lane & 32) >> 1);   // query owned for tree (0..31)
  const int h  = (lane >> 4) & 1;                    // leaf half owned
  const bool lo32 = (lane < 32);

  f32x4 Cac0 = {0.f,0.f,0.f,0.f}, Cac1 = {0.f,0.f,0.f,0.f};

  int cur = 0;
  for (int g = 0; g < G_; ++g) {
    if (g + 1 < G_) {               // fire-and-forget DMA for next group
      const char* src = WbfB + (size_t)(g + 1) * WGB_;
      char* dst = lds + (cur ^ 1) * WGB_;
      #pragma unroll
      for (int it = 0; it < 4; ++it) {
        const int seg = wv * 4096 + it * 1024;
        gload16(src + seg + lane * 16, dst + seg);
      }
    }
    // prefetch per-group operands early
    const short8 Asl = *(const short8*)(slA + (size_t)g * 1024 + lane * 16);
    float sbl[15];
    #pragma unroll
    for (int c = 0; c < 15; ++c) sbl[c] = sbv[g * 15 + c];

    const char* bb = lds + cur * WGB_;
    f32x4 Ch[2], Cm[2];
    #pragma unroll
    for (int rt = 0; rt < 2; ++rt) { Ch[rt] = (f32x4){0,0,0,0}; Cm[rt] = (f32x4){0,0,0,0}; }
    #pragma unroll
    for (int ks = 0; ks < 8; ++ks) {
      const unsigned adr = (unsigned)(lrow * 512 + ks * 64 + lkg * 16) ^ ((unsigned)lrow << 4);
      const short8 bh = *(const short8*)(bb + adr);
      const short8 bl = *(const short8*)(bb + 8192 + adr);
      #pragma unroll
      for (int rt = 0; rt < 2; ++rt) {
        Ch[rt] = __builtin_amdgcn_mfma_f32_16x16x32_bf16(Ah[rt][ks], bh, Ch[rt], 0, 0, 0);
        Cm[rt] = __builtin_amdgcn_mfma_f32_16x16x32_bf16(Ah[rt][ks], bl, Cm[rt], 0, 0, 0);
        Cm[rt] = __builtin_amdgcn_mfma_f32_16x16x32_bf16(Al[rt][ks], bh, Cm[rt], 0, 0, 0);
      }
    }
    // transpose logits through per-wave LDS: [16 i][32 q] f32, swizzled
    #pragma unroll
    for (int rt = 0; rt < 2; ++rt) {
      f32x4 cs;
      #pragma unroll
      for (int r = 0; r < 4; ++r) cs[r] = Ch[rt][r] + Cm[rt][r];
      const unsigned a = (unsigned)(lrow * 128 + (rt * 16 + lkg * 4) * 4) ^ ((unsigned)(lrow & 7) << 4);
      *(f32x4*)(tw + a) = cs;
    }
    // per-lane: 15 logits of query q -> sigmoid -> tree -> 8 leaves (half h)
    float dec[15];
    #pragma unroll
    for (int c = 0; c < 15; ++c) {
      const unsigned a = (unsigned)(c * 128 + q * 4) ^ ((unsigned)(c & 7) << 4);
      const float lg = *(const float*)(tw + a) + sbl[c];
      dec[c] = 1.f / (1.f + __expf(-lg));
    }
    float a_[2], b_[4], c_[8], r8[8];
    a_[0] = 1.f - dec[0]; a_[1] = dec[0];
    #pragma unroll
    for (int j = 0; j < 2; ++j) { b_[2*j] = a_[j] * (1.f - dec[1+j]); b_[2*j+1] = a_[j] * dec[1+j]; }
    #pragma unroll
    for (int j = 0; j < 4; ++j) { c_[2*j] = b_[j] * (1.f - dec[3+j]); c_[2*j+1] = b_[j] * dec[3+j]; }
    #pragma unroll
    for (int j = 0; j < 4; ++j) {
      const int nd = h * 4 + j;
      r8[2*j]   = c_[nd] * (1.f - dec[7+nd]);
      r8[2*j+1] = c_[nd] * dec[7+nd];
    }
    // pack reach to bf16 pairs, build B-frags (tile0 = self, tile1 = xor32)
    const unsigned P0 = cvt_pk_bf16(r8[0], r8[1]);
    const unsigned P1 = cvt_pk_bf16(r8[2], r8[3]);
    const unsigned P2 = cvt_pk_bf16(r8[4], r8[5]);
    const unsigned P3 = cvt_pk_bf16(r8[6], r8[7]);
    const unsigned E0 = __shfl_xor(P0, 32, 64);
    const unsigned E1 = __shfl_xor(P1, 32, 64);
    const unsigned E2 = __shfl_xor(P2, 32, 64);
    const unsigned E3 = __shfl_xor(P3, 32, 64);
    uint4_t b0u = { lo32 ? P0 : 0u, lo32 ? P1 : 0u, lo32 ? P2 : 0u, lo32 ? P3 : 0u };
    uint4_t b1u = { lo32 ? E0 : 0u, lo32 ? E1 : 0u, lo32 ? E2 : 0u, lo32 ? E3 : 0u };
    const short8 B0 = __builtin_bit_cast(short8, b0u);
    const short8 B1 = __builtin_bit_cast(short8, b1u);
    Cac0 = __builtin_amdgcn_mfma_f32_16x16x32_bf16(Asl, B0, Cac0, 0, 0, 0);
    Cac1 = __builtin_amdgcn_mfma_f32_16x16x32_bf16(Asl, B1, Cac1, 0, 0, 0);
    __syncthreads();                // drains DMA (g+1 ready) + all reads of buf[cur] done
    cur ^= 1;
  }

  // store: D[c, q'] col=lane&15, row c=(lane>>4)*4+reg
  const int qcol = lane & 15;
  const int cb   = (lane >> 4) * 4;
  #pragma unroll
  for (int j = 0; j < 4; ++j) {
    const int c = cb + j;
    if (c < 10) {
      out[(size_t)(n0 + wv * 32 + qcol) * 10 + c]      = Cac0[j];
      out[(size_t)(n0 + wv * 32 + 16 + qcol) * 10 + c] = Cac1[j];
    }
  }
}

// ---------------- diagnostic marker: only runs if a launch failed ----------------
__global__ void mark_kernel(float* out, float v) { out[threadIdx.x] = v; }

extern "C" void kernel_launch(void* const* d_in, const int* in_sizes, int n_in,
                              void* d_out, int out_size, void* d_ws, size_t ws_size,
                              hipStream_t stream) {
  (void)in_sizes; (void)n_in; (void)out_size;
  const float* Xs          = (const float*)d_in[0];
  const float* Xq          = (const float*)d_in[1];
  const float* enc_w1      = (const float*)d_in[2];
  const float* enc_b1      = (const float*)d_in[3];
  const float* ln1_g       = (const float*)d_in[4];
  const float* ln1_b       = (const float*)d_in[5];
  const float* enc_w2      = (const float*)d_in[6];
  const float* enc_b2      = (const float*)d_in[7];
  const float* ln2_g       = (const float*)d_in[8];
  const float* ln2_b       = (const float*)d_in[9];
  const float* pg_w1       = (const float*)d_in[10];
  const float* pg_b1       = (const float*)d_in[11];
  const float* pg_ln_g     = (const float*)d_in[12];
  const float* pg_ln_b     = (const float*)d_in[13];
  const float* pg_w2       = (const float*)d_in[14];
  const float* pg_b2       = (const float*)d_in[15];
  const float* head_wts    = (const float*)d_in[16];
  const float* temperature = (const float*)d_in[17];

  float* ws   = (float*)d_ws;
  float* h1   = ws + OFF_H1;
  float* h2   = ws + OFF_H2;
  float* ctx  = ws + OFF_CTX;
  float* pvec = ws + OFF_PVEC;
  float* tmp  = ws + OFF_TMP;
  float* sbp  = ws + OFF_SB;
  float* lrw  = ws + OFF_LRAW;
  float* trw  = ws + OFF_TRAW;
  float* slp  = ws + OFF_SL;
  char*  wbf  = (char*)(ws + OFF_WBF);
  char*  slA  = (char*)(ws + OFF_SLA);
  float* outp = (float*)d_out;

  unsigned mask = 0;
  (void)hipGetLastError();
  if (ws_size < WS_NEED_FLOATS * sizeof(float)) mask |= 0x80u;

  if (!mask) {
    zero_pad_kernel<<<G_, 256, 0, stream>>>(wbf);
    if (hipGetLastError() != hipSuccess) mask |= 1u;
    enc1_kernel<<<dim3(128, 5), 256, 0, stream>>>(Xs, enc_w1, enc_b1, ln1_g, ln1_b, h1);
    if (hipGetLastError() != hipSuccess) mask |= 1u;
    enc2_kernel<<<dim3(128, 5), 256, 0, stream>>>(h1, enc_w2, enc_b2, ln2_g, ln2_b, h2);
    if (hipGetLastError() != hipSuccess) mask |= 2u;
    ctx_kernel<<<5, 256, 0, stream>>>(h2, temperature, ctx, tmp);
    if (hipGetLastError() != hipSuccess) mask |= 4u;
    pvec_kernel<<<5, 128, 0, stream>>>(ctx, pg_w1, pg_b1, pg_ln_g, pg_ln_b, pvec);
    if (hipGetLastError() != hipSuccess) mask |= 8u;
    params_kernel<<<dim3(59, 5), 256, 0, stream>>>(pvec, pg_w2, pg_b2, tmp, wbf, sbp, lrw, trw);
    if (hipGetLastError() != hipSuccess) mask |= 16u;
    finalize_kernel<<<1, 256, 0, stream>>>(head_wts, trw, lrw, tmp, slp, slA);
    if (hipGetLastError() != hipSuccess) mask |= 32u;
    qk_kernel<<<NQ_ / 128, 256, 0, stream>>>(Xq, wbf, slA, sbp, outp);
    if (hipGetLastError() != hipSuccess) mask |= 64u;
  }
  if (mask) {
    mark_kernel<<<1, 16, 0, stream>>>(outp, 1024.f + 4.f * (float)mask);
    (void)hipGetLastError();
  }
}